// Round 2
// baseline (66.055 us; speedup 1.0000x reference)
//
#include <hip/hip_runtime.h>

// VesselIntensitySynth: flip(labels) -> LUT gather -> {intensity plane, 3-way onehot}
// Output layout: d_out = [scaling (D*H*W)] ++ [onehot plane0..2 (3*D*H*W)], float32.

constexpr int VOXELS = 256 * 256 * 256;

// ---------------- host-side Threefry-2x32 (JAX-compatible) ----------------
static inline unsigned rotl32(unsigned x, unsigned r) {
    return (x << r) | (x >> (32u - r));
}

static void threefry2x32(unsigned k0, unsigned k1, unsigned c0, unsigned c1,
                         unsigned* o0, unsigned* o1) {
    const unsigned rotA[4] = {13u, 15u, 26u, 6u};
    const unsigned rotB[4] = {17u, 29u, 16u, 24u};
    unsigned ks[3] = {k0, k1, k0 ^ k1 ^ 0x1BD11BDAu};
    unsigned x0 = c0 + ks[0];
    unsigned x1 = c1 + ks[1];
    for (int g = 0; g < 5; ++g) {
        const unsigned* rot = ((g & 1) == 0) ? rotA : rotB;
        for (int r = 0; r < 4; ++r) {
            x0 += x1;
            x1 = rotl32(x1, rot[r]);
            x1 ^= x0;
        }
        x0 += ks[(g + 1) % 3];
        x1 += ks[(g + 2) % 3] + (unsigned)(g + 1);
    }
    *o0 = x0;
    *o1 = x1;
}

// flips = bernoulli(jax.random.key(1), 0.5, (3,)) under the PARTITIONABLE
// threefry scheme (JAX default since 0.4.36/0.5.x):
//   per element i: counter64 = i -> (c0 = hi = 0, c1 = lo = i)
//   bits_i = out0 ^ out1 of threefry2x32(key=(0,1), (0, i))
//   flip_i = uniform_i < 0.5  <=>  top bit of bits_i == 0
static int jax_flip_bit(unsigned i) {
    unsigned o0, o1;
    threefry2x32(0u, 1u, 0u, i, &o0, &o1);
    return (((o0 ^ o1) >> 31) == 0u) ? 1 : 0;
}

// ---------------- device kernel ----------------
__global__ __launch_bounds__(256) void VesselIntensitySynth_kernel(
    const int* __restrict__ labels,
    const float* __restrict__ ilut,
    const int* __restrict__ clut,
    float* __restrict__ out,
    const int f0, const int f1, const int f2)
{
    // Fused LUT in LDS: (intensity, class-as-float) per id. 512 * 8B = 4 KiB.
    __shared__ float2 lut[512];
    for (int i = threadIdx.x; i < 512; i += 256) {
        lut[i] = make_float2(ilut[i], (float)clut[i]);
    }
    __syncthreads();

    const int t = blockIdx.x * 256 + threadIdx.x;
    const int v = t << 2;                 // base linear OUTPUT voxel index (4/thread)
    const int w = v & 255;
    const int h = (v >> 8) & 255;
    const int d = v >> 16;

    // flipped source coordinates (reads gather, writes stay linear)
    const int sd = f0 ? (255 - d) : d;
    const int sh = f1 ? (255 - h) : h;
    const int sw = f2 ? (252 - w) : w;    // aligned int4 covering reversed run

    const int src = (((sd << 8) | sh) << 8) | sw;
    int4 lab = *reinterpret_cast<const int4*>(labels + src);
    if (f2) {
        int tmp = lab.x; lab.x = lab.w; lab.w = tmp;
        tmp = lab.y;     lab.y = lab.z; lab.z = tmp;
    }

    const float2 e0 = lut[lab.x];
    const float2 e1 = lut[lab.y];
    const float2 e2 = lut[lab.z];
    const float2 e3 = lut[lab.w];

    // plane 0: scaling/intensity
    *reinterpret_cast<float4*>(out + v) =
        make_float4(e0.x, e1.x, e2.x, e3.x);

    // planes 1..3: onehot(class)
    float* oh = out + VOXELS;
    *reinterpret_cast<float4*>(oh + v) = make_float4(
        e0.y == 0.0f ? 1.0f : 0.0f, e1.y == 0.0f ? 1.0f : 0.0f,
        e2.y == 0.0f ? 1.0f : 0.0f, e3.y == 0.0f ? 1.0f : 0.0f);
    *reinterpret_cast<float4*>(oh + VOXELS + v) = make_float4(
        e0.y == 1.0f ? 1.0f : 0.0f, e1.y == 1.0f ? 1.0f : 0.0f,
        e2.y == 1.0f ? 1.0f : 0.0f, e3.y == 1.0f ? 1.0f : 0.0f);
    *reinterpret_cast<float4*>(oh + 2 * VOXELS + v) = make_float4(
        e0.y == 2.0f ? 1.0f : 0.0f, e1.y == 2.0f ? 1.0f : 0.0f,
        e2.y == 2.0f ? 1.0f : 0.0f, e3.y == 2.0f ? 1.0f : 0.0f);
}

extern "C" void kernel_launch(void* const* d_in, const int* in_sizes, int n_in,
                              void* d_out, int out_size, void* d_ws, size_t ws_size,
                              hipStream_t stream) {
    const int*   labels = (const int*)  d_in[0];
    const float* ilut   = (const float*)d_in[1];
    const int*   clut   = (const int*)  d_in[2];
    float*       out    = (float*)      d_out;

    const int f0 = jax_flip_bit(0u);
    const int f1 = jax_flip_bit(1u);
    const int f2 = jax_flip_bit(2u);

    const int threads = 256;
    const int blocks  = VOXELS / 4 / threads;   // 16384
    VesselIntensitySynth_kernel<<<blocks, threads, 0, stream>>>(
        labels, ilut, clut, out, f0, f1, f2);
}